// Round 7
// baseline (110.947 us; speedup 1.0000x reference)
//
#include <hip/hip_runtime.h>
#include <hip/hip_bf16.h>

typedef __attribute__((ext_vector_type(8))) short short8;
typedef __attribute__((ext_vector_type(4))) float f32x4;

#define DDIM 256
#define NROWS 131072
#define ROWS_PER_BLK 128      // 8 waves x 16 rows
#define GBLK ((NROWS / ROWS_PER_BLK) * 2)   // 1024 rowgroups x 2 col-halves

static __device__ __forceinline__ unsigned short f2bf(float f){
  unsigned b = __builtin_bit_cast(unsigned, f);
  b += 0x7FFFu + ((b >> 16) & 1u);          // RNE round to bf16
  return (unsigned short)(b >> 16);
}

// Wave64 sum-reduction via DPP (VALU-only). row_shr 1/2/4/8 then
// row_bcast:15 / row_bcast:31 -> total in lane 63; readlane broadcasts.
static __device__ __forceinline__ float wave_sum_bcast(float x){
  int v = __builtin_bit_cast(int, x);
#define DPP_ADD(ctrl)                                                          \
  v = __builtin_bit_cast(int,                                                  \
        __builtin_bit_cast(float, v) +                                         \
        __builtin_bit_cast(float,                                              \
          __builtin_amdgcn_update_dpp(0, v, (ctrl), 0xF, 0xF, true)))
  DPP_ADD(0x111);  // row_shr:1
  DPP_ADD(0x112);  // row_shr:2
  DPP_ADD(0x114);  // row_shr:4
  DPP_ADD(0x118);  // row_shr:8
  DPP_ADD(0x142);  // row_bcast:15
  DPP_ADD(0x143);  // row_bcast:31
#undef DPP_ADD
  return __builtin_bit_cast(float, __builtin_amdgcn_readlane(v, 63));
}

// ---------------------------------------------------------------------------
// Kernel 0: beta[k] = 2 / ||U[k]||^2.  One wave per row (64 blocks x 4 waves).
// ---------------------------------------------------------------------------
__global__ __launch_bounds__(256) void compute_beta(const float* __restrict__ U,
                                                    float* __restrict__ beta){
  const int lane = threadIdx.x & 63;
  const int k = blockIdx.x * 4 + (threadIdx.x >> 6);
  const f32x4 a = *reinterpret_cast<const f32x4*>(U + (size_t)k * 256 + lane * 4);
  const float s = wave_sum_bcast(a[0]*a[0] + a[1]*a[1] + a[2]*a[2] + a[3]*a[3]);
  if (lane == 0) beta[k] = 2.0f / s;
}

// ---------------------------------------------------------------------------
// Kernel A: Q columns via 256 sequential Householder steps; 2 cols/wave.
// Depth-4 rotating prefetch of U rows + betas hides load latency under
// 4 x ~70cy DPP step bodies.  Writes Q^T (bf16) to Qt[n][k].
// ---------------------------------------------------------------------------
__global__ __launch_bounds__(256) void compute_q(const float* __restrict__ U,
                                                 const float* __restrict__ beta,
                                                 unsigned short* __restrict__ Qt){
  const int lane = threadIdx.x & 63;
  const int wv   = threadIdx.x >> 6;          // 0..3
  const int pair = blockIdx.x * 4 + wv;       // 0..127
  const int j0 = pair * 2, j1 = j0 + 1;

  float u0[4], u1[4], r0[4], r1[4], r2[4], r3[4];
#pragma unroll
  for (int e = 0; e < 4; ++e){
    const int i = e * 64 + lane;
    u0[e] = (i == j0) ? 1.f : 0.f;
    u1[e] = (i == j1) ? 1.f : 0.f;
    r0[e] = U[0 * 256 + i];
    r1[e] = U[1 * 256 + i];
    r2[e] = U[2 * 256 + i];
    r3[e] = U[3 * 256 + i];
  }
  float b0 = beta[0], b1 = beta[1], b2 = beta[2], b3 = beta[3];

#define QSTEP(R, B, KN)                                                        \
  do {                                                                         \
    const float p0_ = (u0[0]*R[0] + u0[1]*R[1]) + (u0[2]*R[2] + u0[3]*R[3]);   \
    const float p1_ = (u1[0]*R[0] + u1[1]*R[1]) + (u1[2]*R[2] + u1[3]*R[3]);   \
    const float d0_ = wave_sum_bcast(p0_);                                     \
    const float d1_ = wave_sum_bcast(p1_);                                     \
    const float c0_ = d0_ * B, c1_ = d1_ * B;                                  \
    _Pragma("unroll")                                                          \
    for (int e = 0; e < 4; ++e){                                               \
      u0[e] = fmaf(-c0_, R[e], u0[e]);                                         \
      u1[e] = fmaf(-c1_, R[e], u1[e]);                                         \
      R[e] = U[(size_t)(KN) * 256 + e * 64 + lane];                            \
    }                                                                          \
    B = beta[(KN)];                                                            \
  } while (0)

  for (int k = 0; k < 256; k += 4){
    const int k4 = (k+4) & 255, k5 = (k+5) & 255, k6 = (k+6) & 255, k7 = (k+7) & 255;
    QSTEP(r0, b0, k4);
    QSTEP(r1, b1, k5);
    QSTEP(r2, b2, k6);
    QSTEP(r3, b3, k7);
  }
#undef QSTEP

#pragma unroll
  for (int e = 0; e < 4; ++e){
    const int i = e * 64 + lane;
    Qt[(size_t)j0 * 256 + i] = f2bf(u0[e]);
    Qt[(size_t)j1 * 256 + i] = f2bf(u1[e]);
  }
}

// ---------------------------------------------------------------------------
// Kernel B: Y = X * Q, N split in halves.  2048 blocks x 512 threads:
// bid = rowgroup*2 + half; block = 128 rows x 128 cols, 8 waves x 16 rows.
// Half of Qt (64 KiB) staged to LDS -> 2 blocks/CU co-resident
// (__launch_bounds__(512,4)) so one block's compute overlaps the other's
// loads.  Consecutive bids are the two halves of the SAME rows -> the
// duplicate X read hits L2/L3 while hot (X = 134 MB < 256 MB L3).
// Full-row XOR swizzle ((nl&15)<<5): B-read slot = (kk*4+lg)^(lm<<1) ->
// 2 lanes/16B slot = conflict-free (verified: SQ_LDS_BANK_CONFLICT=0).
// Stage global loads issue BEFORE the 16 X loads so the ds_write does not
// drain the X-load queue.
// !! 512 threads x 8 iters x 16B = 65536 B = full tile (round-6 bug: 4 iters
//    staged only half the LDS -> NaN from uninitialized B fragments).
// mfma_f32_16x16x32_bf16 layouts (m89/m97):
//   A: lane holds A[l&15][kk*32+8*(l>>4)+j]   B: same, n=l&15
//   D: D[(l>>4)*4+r][l&15]
// ---------------------------------------------------------------------------
__global__ __launch_bounds__(512, 4) void gemm_xq(const float* __restrict__ X,
                                                  const unsigned short* __restrict__ Qt,
                                                  float* __restrict__ Y){
  __shared__ char qb[65536];                  // 128 rows (nl) x 512 B (k, bf16)

  const int tid  = threadIdx.x;
  const int lane = tid & 63;
  const int wv   = tid >> 6;                  // 0..7
  const int lg   = lane >> 4;                 // 0..3
  const int lm   = lane & 15;
  const int half = blockIdx.x & 1;
  const size_t rg = blockIdx.x >> 1;
  const size_t row0 = rg * ROWS_PER_BLK + wv * 16;

  // --- Stage loads first (8 x 16B per thread, coalesced from L2) ---
  f32x4 sv[8];
#pragma unroll
  for (int it = 0; it < 8; ++it){
    const int c = tid + it * 512;             // 0..4095 chunks of 16B
    sv[it] = *reinterpret_cast<const f32x4*>(
        reinterpret_cast<const char*>(Qt) +
        ((size_t)(half * 128) << 9) + ((size_t)c << 4));
  }

  // --- X row loads (16 x 16B per thread) ---
  const float* xp = X + (row0 + lm) * DDIM + lg * 8;
  f32x4 xv[16];
#pragma unroll
  for (int kk = 0; kk < 8; ++kk){
    xv[2*kk]   = *reinterpret_cast<const f32x4*>(xp + kk * 32);
    xv[2*kk+1] = *reinterpret_cast<const f32x4*>(xp + kk * 32 + 4);
  }

  // --- LDS writes (swizzled) + barrier ---
#pragma unroll
  for (int it = 0; it < 8; ++it){
    const int c   = tid + it * 512;
    const int n   = c >> 5;                   // local row nl (0..127)
    const int off = (c & 31) << 4;            // byte offset within 512B row
    *reinterpret_cast<f32x4*>(qb + (n << 9) + (off ^ ((n & 15) << 5))) = sv[it];
  }
  __syncthreads();

  f32x4 acc[8];
#pragma unroll
  for (int nt = 0; nt < 8; ++nt) acc[nt] = (f32x4){0.f, 0.f, 0.f, 0.f};

#pragma unroll
  for (int kk = 0; kk < 8; ++kk){
    const f32x4 lo = xv[2*kk], hi = xv[2*kk+1];
    short8 a;
    a[0] = (short)f2bf(lo[0]); a[1] = (short)f2bf(lo[1]);
    a[2] = (short)f2bf(lo[2]); a[3] = (short)f2bf(lo[3]);
    a[4] = (short)f2bf(hi[0]); a[5] = (short)f2bf(hi[1]);
    a[6] = (short)f2bf(hi[2]); a[7] = (short)f2bf(hi[3]);

    const int kb = kk * 64 + (lg << 4);       // byte offset of lane's 8 bf16 in k
#pragma unroll
    for (int nt = 0; nt < 8; ++nt){
      const int nl = nt * 16 + lm;            // local col 0..127
      const short8 b = *reinterpret_cast<const short8*>(
          qb + (nl << 9) + (kb ^ ((nl & 15) << 5)));
      acc[nt] = __builtin_amdgcn_mfma_f32_16x16x32_bf16(a, b, acc[nt], 0, 0, 0);
    }
  }

  // Epilogue: D[(l>>4)*4+r][l&15] per 16x16 tile.
  const size_t orow = row0 + lg * 4;
  const int col0 = half * 128;
#pragma unroll
  for (int nt = 0; nt < 8; ++nt){
#pragma unroll
    for (int r = 0; r < 4; ++r){
      Y[(orow + r) * DDIM + col0 + nt * 16 + lm] = acc[nt][r];
    }
  }
}

extern "C" void kernel_launch(void* const* d_in, const int* in_sizes, int n_in,
                              void* d_out, int out_size, void* d_ws, size_t ws_size,
                              hipStream_t stream) {
  const float* X = (const float*)d_in[0];     // [131072, 256]
  const float* U = (const float*)d_in[1];     // [256, 256]
  float* Y = (float*)d_out;                   // [131072, 256]
  unsigned short* Qt = (unsigned short*)d_ws; // 256*256 bf16 = 128 KB scratch

  // beta lives in the tail of d_out: consumed by compute_q (stream-ordered)
  // before gemm_xq overwrites all of d_out.
  float* beta = (float*)d_out + ((size_t)out_size - 256);

  compute_beta<<<64, 256, 0, stream>>>(U, beta);
  compute_q<<<32, 256, 0, stream>>>(U, beta, Qt);
  gemm_xq<<<GBLK, 512, 0, stream>>>(X, Qt, Y);
}